// Round 1
// baseline (4375.979 us; speedup 1.0000x reference)
//
#include <hip/hip_runtime.h>

#define NN   729
#define NF   730   // N+1
#define BV   8
#define KK   32
#define NBAS 40
#define MAXIT 10
#define PI_F 3.14159265358979323846f

#define MIX_THREADS 1024
#define GM 23   // ceil(730/32) rows of G per thread

// ---------------- build C (730x730) and its transpose CT ----------------
__global__ void build_C_kernel(const float* __restrict__ coeff,
                               const float* __restrict__ upper,
                               const float* __restrict__ basis,
                               float* __restrict__ C, float* __restrict__ CT) {
    int idx = blockIdx.x * blockDim.x + threadIdx.x;
    if (idx >= NF * NF) return;
    int i = idx / NF, j = idx - i * NF;
    float val;
    if (i == 0) {
        val = (j == 0) ? 0.f : upper[j - 1];
    } else if (j == 0) {
        val = upper[i - 1];
    } else {
        float acc = 0.f;
        const float* bp = basis + (size_t)(i - 1) * NN + (j - 1);
        #pragma unroll 8
        for (int b = 0; b < NBAS; ++b)
            acc = fmaf(coeff[b], bp[(size_t)b * NN * NN], acc);
        val = acc;
    }
    C[idx] = val;
    CT[(size_t)j * NF + i] = val;
}

// ---------------- init V  (B x 730 x 32) ----------------
__global__ void init_V_kernel(const float* __restrict__ z,
                              const float* __restrict__ vraw,
                              float* __restrict__ V) {
    // 730 blocks x 256 threads; each 32-thread group handles one (b,n)
    int g = threadIdx.x >> 5;
    int k = threadIdx.x & 31;
    int row = blockIdx.x * 8 + g;           // 0..5839
    int b = row / NF, n = row - b * NF;
    const float* vr = vraw + (size_t)b * NF * KK;

    float v0 = vr[k];                        // row 0
    float s2 = v0 * v0;
    #pragma unroll
    for (int off = 16; off; off >>= 1) s2 += __shfl_xor(s2, off, 32);
    v0 = v0 / sqrtf(s2);

    float vn = vr[(size_t)n * KK + k];
    float d = vn * v0;
    #pragma unroll
    for (int off = 16; off; off >>= 1) d += __shfl_xor(d, off, 32);
    float u = vn - d * v0;
    float un2 = u * u;
    #pragma unroll
    for (int off = 16; off; off >>= 1) un2 += __shfl_xor(un2, off, 32);
    u = u / fmaxf(sqrtf(un2), 1e-8f);

    float zf = (n == 0) ? 1.f : z[b * NN + (n - 1)];
    float c = cosf(PI_F * zf), s = sinf(PI_F * zf);
    float outv = -c * v0 + s * u;
    if (n == 0) outv = v0;
    V[((size_t)b * NF + n) * KK + k] = outv;
}

// ---------------- init G = C^T V  (B x 730 x 32) ----------------
__global__ void init_G_kernel(const float* __restrict__ CT,
                              const float* __restrict__ V,
                              float* __restrict__ G) {
    // grid (92, 8), block 256 = 8 i' rows x 32 k
    int k = threadIdx.x & 31;
    int isub = threadIdx.x >> 5;
    int i = blockIdx.x * 8 + isub;
    int b = blockIdx.y;
    if (i >= NF) return;
    const float* ct = CT + (size_t)i * NF;
    const float* v  = V + (size_t)b * NF * KK + k;
    float acc = 0.f;
    for (int j = 0; j < NF; ++j)
        acc = fmaf(ct[j], v[(size_t)j * KK], acc);
    G[((size_t)b * NF + i) * KK + k] = acc;
}

// ---------------- sequential mixing, one workgroup per batch ----------------
__global__ __launch_bounds__(MIX_THREADS)
void mix_kernel(const float* __restrict__ C,
                const int* __restrict__ is_input,
                const int* __restrict__ perm,
                const float* __restrict__ z,
                const float* __restrict__ Vg,
                const float* __restrict__ Gg,
                float* __restrict__ out) {
    __shared__ float V_lds[NF * KK];   // 93440 B
    __shared__ float Cd[NF];
    __shared__ int   act[NN];
    __shared__ int   pstage[NN];
    __shared__ float gbuf[KK];
    __shared__ float dvbuf[KK];
    __shared__ int   nA_s;

    int b = blockIdx.x;
    int tid = threadIdx.x;
    int k = tid & 31;
    int r = tid >> 5;      // 0..31: G row-group (rows j = r + 32*m)

    // stage V, diag(C), perm
    for (int idx = tid; idx < NF * KK; idx += MIX_THREADS)
        V_lds[idx] = Vg[(size_t)b * NF * KK + idx];
    for (int i = tid; i < NF; i += MIX_THREADS)
        Cd[i] = C[(size_t)i * NF + i];
    if (tid < NN) pstage[tid] = perm[tid];

    // load G into registers
    float Greg[GM];
    #pragma unroll
    for (int m = 0; m < GM; ++m) {
        int j = r + 32 * m;
        Greg[m] = (j < NF) ? Gg[((size_t)b * NF + j) * KK + k] : 0.f;
    }
    __syncthreads();

    // gather free-flags, then thread 0 builds active list (perm order)
    if (tid < NN) {
        int pi = pstage[tid];
        int ii = is_input[b * NN + (pi - 1)];
        pstage[tid] = pi | (ii << 16);
    }
    __syncthreads();
    if (tid == 0) {
        int cnt = 0;
        for (int s = 0; s < NN; ++s) {
            int v = pstage[s];
            if (!(v >> 16)) act[cnt++] = v & 0xFFFF;
        }
        nA_s = cnt;
    }
    __syncthreads();
    int nA = nA_s;

    if (nA > 0) {
        int i0 = act[0];
        // prologue: owners of row i0 publish g_eff, everyone prefetches C row i0
        if (r == (i0 & 31)) {
            int mext = i0 >> 5;
            float val = 0.f;
            #pragma unroll
            for (int mm = 0; mm < GM; ++mm) if (mm == mext) val = Greg[mm];
            gbuf[k] = val - Cd[i0] * V_lds[i0 * KK + k];
        }
        float crow[GM];
        {
            const float* Crow = C + (size_t)i0 * NF;
            #pragma unroll
            for (int m = 0; m < GM; ++m) {
                int j = r + 32 * m;
                crow[m] = (j < NF) ? Crow[j] : 0.f;
            }
        }

        for (int sweep = 0; sweep < MAXIT; ++sweep) {
            for (int s = 0; s < nA; ++s) {
                int i = act[s];
                int i_next = (s + 1 < nA) ? act[s + 1] : act[0];

                __syncthreads();   // gbuf for step s is ready
                if (tid < 32) {
                    float gk = gbuf[k];
                    float n2 = gk * gk;
                    #pragma unroll
                    for (int off = 16; off; off >>= 1) n2 += __shfl_xor(n2, off, 32);
                    float inv = -1.f / fmaxf(sqrtf(n2), 1e-8f);
                    float vnk = gk * inv;
                    dvbuf[k] = vnk - V_lds[i * KK + k];
                    V_lds[i * KK + k] = vnk;
                }
                __syncthreads();   // dvbuf + V row i ready

                float dvk = dvbuf[k];
                #pragma unroll
                for (int m = 0; m < GM; ++m)
                    Greg[m] = fmaf(crow[m], dvk, Greg[m]);

                // owners of next row publish its g_eff (after applying this update)
                if (r == (i_next & 31)) {
                    int mext = i_next >> 5;
                    float val = 0.f;
                    #pragma unroll
                    for (int mm = 0; mm < GM; ++mm) if (mm == mext) val = Greg[mm];
                    gbuf[k] = val - Cd[i_next] * V_lds[i_next * KK + k];
                }
                // prefetch C row for next step
                {
                    const float* Crow = C + (size_t)i_next * NF;
                    #pragma unroll
                    for (int m = 0; m < GM; ++m) {
                        int j = r + 32 * m;
                        crow[m] = (j < NF) ? Crow[j] : 0.f;
                    }
                }
            }
        }
    }
    __syncthreads();

    // output: 32 groups of 32 lanes; group r handles rows n = 1+r, 1+r+32, ...
    float v0k = V_lds[k];
    for (int n = 1 + r; n <= NN; n += 32) {
        float dot = V_lds[n * KK + k] * v0k;
        #pragma unroll
        for (int off = 16; off; off >>= 1) dot += __shfl_xor(dot, off, 32);
        if (k == 0) {
            int ii = is_input[b * NN + (n - 1)];
            float zo;
            if (ii == 1) {
                zo = z[b * NN + (n - 1)];
            } else {
                float ca = -dot;
                ca = fminf(fmaxf(ca, -1.f + 1e-6f), 1.f - 1e-6f);
                zo = acosf(ca) * (1.f / PI_F);
            }
            out[b * NN + (n - 1)] = zo;
        }
    }
}

extern "C" void kernel_launch(void* const* d_in, const int* in_sizes, int n_in,
                              void* d_out, int out_size, void* d_ws, size_t ws_size,
                              hipStream_t stream) {
    const float* coeff    = (const float*)d_in[0];
    const float* upper    = (const float*)d_in[1];
    const float* basis    = (const float*)d_in[2];
    const float* z        = (const float*)d_in[3];
    const int*   is_input = (const int*)d_in[4];
    const float* vraw     = (const float*)d_in[5];
    const int*   perm     = (const int*)d_in[6];
    float* out = (float*)d_out;

    float* ws = (float*)d_ws;
    float* C  = ws;                       // 730*730
    float* CT = C + (size_t)NF * NF;      // 730*730
    float* V  = CT + (size_t)NF * NF;     // 8*730*32
    float* G  = V + (size_t)BV * NF * KK; // 8*730*32

    build_C_kernel<<<dim3((NF * NF + 255) / 256), dim3(256), 0, stream>>>(coeff, upper, basis, C, CT);
    init_V_kernel<<<dim3(730), dim3(256), 0, stream>>>(z, vraw, V);
    init_G_kernel<<<dim3(92, 8), dim3(256), 0, stream>>>(CT, V, G);
    mix_kernel<<<dim3(BV), dim3(MIX_THREADS), 0, stream>>>(C, is_input, perm, z, V, G, out);
}

// Round 2
// 4142.669 us; speedup vs baseline: 1.0563x; 1.0563x over previous
//
#include <hip/hip_runtime.h>

#define NN   729
#define NF   730   // N+1
#define BV   8
#define KK   32
#define NBAS 40
#define MAXIT 10
#define PI_F 3.14159265358979323846f

#define MTH  1024   // mix threads
#define MAXA 512    // max active rows supported (actual ~365)
#define BT   16     // steps per block
#define WST  36     // W row stride in floats (pad vs 32 to stagger banks)

// ---------------- build C (730x730) and its transpose CT ----------------
__global__ void build_C_kernel(const float* __restrict__ coeff,
                               const float* __restrict__ upper,
                               const float* __restrict__ basis,
                               float* __restrict__ C, float* __restrict__ CT) {
    int idx = blockIdx.x * blockDim.x + threadIdx.x;
    if (idx >= NF * NF) return;
    int i = idx / NF, j = idx - i * NF;
    float val;
    if (i == 0) {
        val = (j == 0) ? 0.f : upper[j - 1];
    } else if (j == 0) {
        val = upper[i - 1];
    } else {
        float acc = 0.f;
        const float* bp = basis + (size_t)(i - 1) * NN + (j - 1);
        #pragma unroll 8
        for (int b = 0; b < NBAS; ++b)
            acc = fmaf(coeff[b], bp[(size_t)b * NN * NN], acc);
        val = acc;
    }
    C[idx] = val;
    CT[(size_t)j * NF + i] = val;
}

// ---------------- init V  (B x 730 x 32) ----------------
__global__ void init_V_kernel(const float* __restrict__ z,
                              const float* __restrict__ vraw,
                              float* __restrict__ V) {
    int g = threadIdx.x >> 5;
    int k = threadIdx.x & 31;
    int row = blockIdx.x * 8 + g;           // 0..5839
    int b = row / NF, n = row - b * NF;
    const float* vr = vraw + (size_t)b * NF * KK;

    float v0 = vr[k];
    float s2 = v0 * v0;
    #pragma unroll
    for (int off = 16; off; off >>= 1) s2 += __shfl_xor(s2, off, 32);
    v0 = v0 / sqrtf(s2);

    float vn = vr[(size_t)n * KK + k];
    float d = vn * v0;
    #pragma unroll
    for (int off = 16; off; off >>= 1) d += __shfl_xor(d, off, 32);
    float u = vn - d * v0;
    float un2 = u * u;
    #pragma unroll
    for (int off = 16; off; off >>= 1) un2 += __shfl_xor(un2, off, 32);
    u = u / fmaxf(sqrtf(un2), 1e-8f);

    float zf = (n == 0) ? 1.f : z[b * NN + (n - 1)];
    float c = cosf(PI_F * zf), s = sinf(PI_F * zf);
    float outv = -c * v0 + s * u;
    if (n == 0) outv = v0;
    V[((size_t)b * NF + n) * KK + k] = outv;
}

// ---------------- init G = C^T V  (B x 730 x 32) ----------------
__global__ void init_G_kernel(const float* __restrict__ CT,
                              const float* __restrict__ V,
                              float* __restrict__ G) {
    int k = threadIdx.x & 31;
    int isub = threadIdx.x >> 5;
    int i = blockIdx.x * 8 + isub;
    int b = blockIdx.y;
    if (i >= NF) return;
    const float* ct = CT + (size_t)i * NF;
    const float* v  = V + (size_t)b * NF * KK + k;
    float acc = 0.f;
    for (int j = 0; j < NF; ++j)
        acc = fmaf(ct[j], v[(size_t)j * KK], acc);
    G[((size_t)b * NF + i) * KK + k] = acc;
}

// ---------------- mixing: compact W in LDS, 16-step blocks ----------------
__global__ __launch_bounds__(MTH)
void mix_kernel(const float* __restrict__ C,
                const int* __restrict__ is_input,
                const int* __restrict__ perm,
                const float* __restrict__ z,
                const float* __restrict__ Vg,
                const float* __restrict__ Gg,
                float* __restrict__ out) {
    __shared__ __align__(16) float W_c[MAXA * WST];   // 73728 B
    __shared__ __align__(16) float V_c[MAXA * KK];    // 65536 B
    __shared__ __align__(16) float dv_s[BT * KK];     // 2048 B
    __shared__ float Cblk[BT * BT];                   // 1024 B
    __shared__ float Cdc[MAXA];                       // 2048 B
    __shared__ int   act_s[NN];                       // 2916 B
    __shared__ int   slot_s[NF];                      // 2920 B
    __shared__ int   nA_sh;

    int b = blockIdx.x, tid = threadIdx.x;
    int k = tid & 31, r = tid >> 5;

    // ---- build active list (perm order) ----
    if (tid < NN) {
        int pi = perm[tid];
        int ii = is_input[b * NN + pi - 1];
        slot_s[tid] = pi | (ii << 16);      // slot_s doubles as staging
    }
    __syncthreads();
    if (tid == 0) {
        int cnt = 0;
        for (int s = 0; s < NN; ++s) {
            int v = slot_s[s];
            if (!(v >> 16) && cnt < MAXA) act_s[cnt++] = v & 0xFFFF;
        }
        nA_sh = cnt;
    }
    __syncthreads();
    int nA = nA_sh;

    // ---- fill W = G - Cd*V, V, slot map, Cdc ----
    for (int idx = tid; idx < nA * KK; idx += MTH) {
        int a = idx >> 5, k2 = idx & 31;
        int ia = act_s[a];
        float vv = Vg[((size_t)b * NF + ia) * KK + k2];
        float gg = Gg[((size_t)b * NF + ia) * KK + k2];
        float cd = C[(size_t)ia * NF + ia];
        W_c[a * WST + k2] = gg - cd * vv;
        V_c[a * KK + k2] = vv;
        if (k2 == 0) { slot_s[ia] = a; Cdc[a] = cd; }
    }
    // Cblk for block 0
    if (tid < BT * BT) {
        int tt = tid >> 4, uu = tid & 15;
        Cblk[tid] = (tt < nA && uu < nA)
                  ? C[(size_t)act_s[tt] * NF + act_s[uu]] : 0.f;
    }
    __syncthreads();

    int nblk = (nA + BT - 1) / BT;
    int totB = MAXIT * nblk;
    int k4 = tid & 7, r4 = tid >> 3;

    for (int bi = 0; bi < totB; ++bi) {
        int s0 = (bi % nblk) * BT;
        int Tb = min(BT, nA - s0);

        // ---- serial phase: wave 0 runs Tb steps with in-block corrections ----
        if (tid < 32) {
            float gnext = W_c[s0 * WST + k];
            for (int u = 0; u < Tb; ++u) {
                int s = s0 + u;
                float g = gnext;
                if (u + 1 < Tb) gnext = W_c[(s + 1) * WST + k];
                for (int t = 0; t < u; ++t)
                    g = fmaf(Cblk[t * BT + u], dv_s[t * KK + k], g);
                float n2 = g * g;
                #pragma unroll
                for (int off = 16; off; off >>= 1) n2 += __shfl_xor(n2, off, 32);
                float inv = -1.f / fmaxf(sqrtf(n2), 1e-8f);
                float vnk = g * inv;
                dv_s[u * KK + k] = vnk - V_c[s * KK + k];
                V_c[s * KK + k] = vnk;
            }
        }
        __syncthreads();

        // ---- prefetch next block's Cblk (issue loads before bulk) ----
        bool dopre = (tid < BT * BT) && (bi + 1 < totB);
        float cpre = 0.f;
        if (dopre) {
            int s0n = ((bi + 1) % nblk) * BT;
            int tt = tid >> 4, uu = tid & 15;
            int st = s0n + tt, su = s0n + uu;
            cpre = (st < nA && su < nA)
                 ? C[(size_t)act_s[st] * NF + act_s[su]] : 0.f;
        }

        // ---- bulk rank-Tb update of W (float4 per thread) ----
        int rowb[BT];
        #pragma unroll
        for (int t = 0; t < BT; ++t)
            rowb[t] = (t < Tb) ? act_s[s0 + t] * NF : 0;

        int mcnt = (nA + 127) >> 7;
        for (int m = 0; m < mcnt; ++m) {
            int a = r4 + (m << 7);
            if (a < nA) {
                int ia = act_s[a];
                float4 w = *(const float4*)(W_c + a * WST + k4 * 4);
                #pragma unroll
                for (int t = 0; t < BT; ++t) {
                    if (t < Tb) {
                        float c = C[(size_t)rowb[t] + ia];
                        float4 d = *(const float4*)(dv_s + t * KK + k4 * 4);
                        w.x = fmaf(c, d.x, w.x); w.y = fmaf(c, d.y, w.y);
                        w.z = fmaf(c, d.z, w.z); w.w = fmaf(c, d.w, w.w);
                    }
                }
                if (a >= s0 && a < s0 + Tb) {   // cancel self-term
                    float cd = Cdc[a];
                    float4 d = *(const float4*)(dv_s + (a - s0) * KK + k4 * 4);
                    w.x = fmaf(-cd, d.x, w.x); w.y = fmaf(-cd, d.y, w.y);
                    w.z = fmaf(-cd, d.z, w.z); w.w = fmaf(-cd, d.w, w.w);
                }
                *(float4*)(W_c + a * WST + k4 * 4) = w;
            }
        }
        if (dopre) Cblk[tid] = cpre;
        __syncthreads();
    }

    // ---- epilogue: z_out ----
    float v0k = Vg[(size_t)b * NF * KK + k];
    for (int n = 1 + r; n <= NN; n += 32) {
        int ii = is_input[b * NN + n - 1];
        float res;
        if (ii == 1) {
            res = z[b * NN + n - 1];
        } else {
            int a = slot_s[n];
            float dot = V_c[a * KK + k] * v0k;
            #pragma unroll
            for (int off = 16; off; off >>= 1) dot += __shfl_xor(dot, off, 32);
            float ca = fminf(fmaxf(-dot, -1.f + 1e-6f), 1.f - 1e-6f);
            res = acosf(ca) * (1.f / PI_F);
        }
        if (k == 0) out[b * NN + n - 1] = res;
    }
}

extern "C" void kernel_launch(void* const* d_in, const int* in_sizes, int n_in,
                              void* d_out, int out_size, void* d_ws, size_t ws_size,
                              hipStream_t stream) {
    const float* coeff    = (const float*)d_in[0];
    const float* upper    = (const float*)d_in[1];
    const float* basis    = (const float*)d_in[2];
    const float* z        = (const float*)d_in[3];
    const int*   is_input = (const int*)d_in[4];
    const float* vraw     = (const float*)d_in[5];
    const int*   perm     = (const int*)d_in[6];
    float* out = (float*)d_out;

    float* ws = (float*)d_ws;
    float* C  = ws;                       // 730*730
    float* CT = C + (size_t)NF * NF;      // 730*730
    float* V  = CT + (size_t)NF * NF;     // 8*730*32
    float* G  = V + (size_t)BV * NF * KK; // 8*730*32

    build_C_kernel<<<dim3((NF * NF + 255) / 256), dim3(256), 0, stream>>>(coeff, upper, basis, C, CT);
    init_V_kernel<<<dim3(730), dim3(256), 0, stream>>>(z, vraw, V);
    init_G_kernel<<<dim3(92, 8), dim3(256), 0, stream>>>(CT, V, G);
    mix_kernel<<<dim3(BV), dim3(MTH), 0, stream>>>(C, is_input, perm, z, V, G, out);
}

// Round 4
// 1145.629 us; speedup vs baseline: 3.8197x; 3.6161x over previous
//
#include <hip/hip_runtime.h>

#define NN   729
#define NF   730   // N+1
#define BV   8
#define KK   32
#define NBAS 40
#define MAXIT 10
#define PI_F 3.14159265358979323846f

#define MTH  512    // mix threads (8 waves)
#define BT   16     // steps per block
#define AST  448    // padded max active rows (mean ~365); Cact stride
#define WST  36     // W row stride (floats), breaks bank alignment

__device__ __forceinline__ void fma4(float4& a, float c, const float4& d) {
    a.x = fmaf(c, d.x, a.x); a.y = fmaf(c, d.y, a.y);
    a.z = fmaf(c, d.z, a.z); a.w = fmaf(c, d.w, a.w);
}

// ---------------- build Ct (730x730), Ct[i][j] = C[j][i] ----------------
__global__ void build_C_kernel(const float* __restrict__ coeff,
                               const float* __restrict__ upper,
                               const float* __restrict__ basis,
                               float* __restrict__ Ct) {
    int idx = blockIdx.x * blockDim.x + threadIdx.x;
    if (idx >= NF * NF) return;
    int i = idx / NF, j = idx - i * NF;   // (i,j) of C; coalesced basis reads
    float val;
    if (i == 0) {
        val = (j == 0) ? 0.f : upper[j - 1];
    } else if (j == 0) {
        val = upper[i - 1];
    } else {
        float acc = 0.f;
        const float* bp = basis + (size_t)(i - 1) * NN + (j - 1);
        #pragma unroll 8
        for (int b = 0; b < NBAS; ++b)
            acc = fmaf(coeff[b], bp[(size_t)b * NN * NN], acc);
        val = acc;
    }
    Ct[(size_t)j * NF + i] = val;
}

// ---------------- init V  (B x 730 x 32) ----------------
__global__ void init_V_kernel(const float* __restrict__ z,
                              const float* __restrict__ vraw,
                              float* __restrict__ V) {
    int g = threadIdx.x >> 5;
    int k = threadIdx.x & 31;
    int row = blockIdx.x * 8 + g;           // 0..5839
    int b = row / NF, n = row - b * NF;
    const float* vr = vraw + (size_t)b * NF * KK;

    float v0 = vr[k];
    float s2 = v0 * v0;
    #pragma unroll
    for (int off = 16; off; off >>= 1) s2 += __shfl_xor(s2, off, 32);
    v0 = v0 / sqrtf(s2);

    float vn = vr[(size_t)n * KK + k];
    float d = vn * v0;
    #pragma unroll
    for (int off = 16; off; off >>= 1) d += __shfl_xor(d, off, 32);
    float u = vn - d * v0;
    float un2 = u * u;
    #pragma unroll
    for (int off = 16; off; off >>= 1) un2 += __shfl_xor(un2, off, 32);
    u = u / fmaxf(sqrtf(un2), 1e-8f);

    float zf = (n == 0) ? 1.f : z[b * NN + (n - 1)];
    float c = cosf(PI_F * zf), s = sinf(PI_F * zf);
    float outv = -c * v0 + s * u;
    if (n == 0) outv = v0;
    V[((size_t)b * NF + n) * KK + k] = outv;
}

// ---------------- build per-batch active lists (perm order) ----------------
__global__ void build_act_kernel(const int* __restrict__ is_input,
                                 const int* __restrict__ perm,
                                 int* __restrict__ act, int* __restrict__ nA_arr) {
    int b = blockIdx.x, l = threadIdx.x;   // 64 threads = 1 wave
    int base = 0;
    for (int c = 0; c < (NN + 63) / 64; ++c) {
        int idx = c * 64 + l;
        bool f = false; int pi = 0;
        if (idx < NN) { pi = perm[idx]; f = (is_input[b * NN + pi - 1] == 0); }
        unsigned long long m = __ballot(f);
        int pos = __popcll(m & ((1ull << l) - 1ull));
        if (f && base + pos < AST) act[b * AST + base + pos] = pi;
        base += __popcll(m);
    }
    if (base > AST) base = AST;
    if (l == 0) nA_arr[b] = base;
    for (int p = base + l; p < AST; p += 64) act[b * AST + p] = 0;
}

// ------- gather Cact[b][t][a] = C[act_t][act_a] = Ct[act_a][act_t] -------
__global__ void gather_Cact_kernel(const float* __restrict__ Ct,
                                   const int* __restrict__ act,
                                   float* __restrict__ Cact) {
    int t = blockIdx.x, b = blockIdx.y;
    __shared__ int acts[AST];
    for (int i = threadIdx.x; i < AST; i += blockDim.x) acts[i] = act[b * AST + i];
    __syncthreads();
    int ct_col = acts[t];
    float* dst = Cact + ((size_t)b * AST + t) * AST;
    for (int a = threadIdx.x; a < AST; a += blockDim.x)
        dst[a] = Ct[(size_t)acts[a] * NF + ct_col];
}

// ------- init W (compact): W[a] = sum_j Ct[ra][j] V[j] - Cd V[ra] -------
__global__ void init_W_kernel(const float* __restrict__ Ct,
                              const int* __restrict__ act,
                              const int* __restrict__ nA_arr,
                              const float* __restrict__ V,
                              float* __restrict__ Wc) {
    int b = blockIdx.y;
    int a = blockIdx.x * 8 + (threadIdx.x >> 5);
    int k = threadIdx.x & 31;
    int nA = nA_arr[b];
    float w = 0.f;
    if (a < nA) {
        int ra = act[b * AST + a];
        const float* ctr = Ct + (size_t)ra * NF;
        const float* vb = V + (size_t)b * NF * KK + k;
        float acc = 0.f;
        for (int j = 0; j < NF; ++j)
            acc = fmaf(ctr[j], vb[(size_t)j * KK], acc);
        float cd = ctr[ra];
        w = acc - cd * V[((size_t)b * NF + ra) * KK + k];
    }
    Wc[((size_t)b * AST + a) * KK + k] = w;
}

// 16-lane row sum via DPP row rotations (pure VALU)
__device__ __forceinline__ float rowsum16(float x) {
    int y;
    y = __builtin_amdgcn_update_dpp(0, __float_as_int(x), 0x121, 0xF, 0xF, false);
    x += __int_as_float(y);
    y = __builtin_amdgcn_update_dpp(0, __float_as_int(x), 0x122, 0xF, 0xF, false);
    x += __int_as_float(y);
    y = __builtin_amdgcn_update_dpp(0, __float_as_int(x), 0x124, 0xF, 0xF, false);
    x += __int_as_float(y);
    y = __builtin_amdgcn_update_dpp(0, __float_as_int(x), 0x128, 0xF, 0xF, false);
    x += __int_as_float(y);
    return x;
}

// ---------------- mixing ----------------
__global__ __launch_bounds__(MTH, 2)
void mix_kernel(const float* __restrict__ Cact_g,
                const float* __restrict__ Wc,
                const int* __restrict__ act_g,
                const int* __restrict__ nA_arr,
                const int* __restrict__ is_input,
                const float* __restrict__ z,
                const float* __restrict__ Vg,
                float* __restrict__ out) {
    __shared__ float W_c[AST * WST];      // 64512 B
    __shared__ float V_c[AST * KK];       // 57344 B
    __shared__ float dv_s[2][BT * KK];    // 4096 B
    __shared__ float cblk_s[2][BT * BT];  // 2048 B
    __shared__ int   act_s[AST];          // 1792 B
    __shared__ int   slot_s[NF];          // 2920 B

    int b = blockIdx.x, tid = threadIdx.x;
    const float* Cact = Cact_g + (size_t)b * AST * AST;
    int nA = nA_arr[b];
    int nblkp = (nA + BT - 1) / BT;
    if (nblkp < 1) nblkp = 1;
    int nAp = nblkp * BT;
    int totB = MAXIT * nblkp;

    if (tid < AST) act_s[tid] = act_g[b * AST + tid];
    __syncthreads();
    for (int idx = tid; idx < nAp * KK; idx += MTH) {
        int a = idx >> 5, k = idx & 31;
        V_c[idx] = Vg[((size_t)b * NF + act_s[a]) * KK + k];
        W_c[a * WST + k] = Wc[((size_t)b * AST + a) * KK + k];
    }
    if (tid < nA) slot_s[act_s[tid]] = tid;
    if (tid < BT * BT)
        cblk_s[0][tid] = Cact[(size_t)(tid >> 4) * AST + (tid & 15)];
    __syncthreads();

    int wid = tid >> 6;

    for (int bi = 0; bi < totB; ++bi) {
        int blk = bi % nblkp;
        int s0 = blk * BT;
        int pblk = (bi - 1) % nblkp;    // only valid when bi > 0
        int sp0 = pblk * BT;
        int cb = bi & 1, pv = cb ^ 1;

        if (wid == 0) {
            // ---- phase A: own block's 16 rows += prev dv (rank-16) ----
            if (bi > 0) {
                int u = tid >> 2, kq = (tid & 3) * 8;
                float4 wA = *(float4*)&W_c[(s0 + u) * WST + kq];
                float4 wB = *(float4*)&W_c[(s0 + u) * WST + kq + 4];
                #pragma unroll
                for (int t = 0; t < BT; ++t) {
                    float c = Cact[(size_t)(sp0 + t) * AST + (s0 + u)];
                    float4 dA = *(float4*)&dv_s[pv][t * KK + kq];
                    float4 dB = *(float4*)&dv_s[pv][t * KK + kq + 4];
                    fma4(wA, c, dA);
                    fma4(wB, c, dB);
                }
                *(float4*)&W_c[(s0 + u) * WST + kq] = wA;
                *(float4*)&W_c[(s0 + u) * WST + kq + 4] = wB;
            }
            __builtin_amdgcn_wave_barrier();

            // ---- serial: 16 steps, dv in registers, DPP norm ----
            int ll = tid & 15;
            float dv0[BT], dv1[BT];
            #pragma unroll
            for (int u = 0; u < BT; ++u) {
                int s = s0 + u;
                float g0 = W_c[s * WST + ll];
                float g1 = W_c[s * WST + ll + 16];
                #pragma unroll
                for (int t = 0; t < u; ++t) {
                    float c = cblk_s[cb][t * BT + u];
                    g0 = fmaf(c, dv0[t], g0);
                    g1 = fmaf(c, dv1[t], g1);
                }
                float n2 = fmaf(g0, g0, g1 * g1);
                n2 = rowsum16(n2);
                float inv = -1.f / fmaxf(sqrtf(n2), 1e-8f);
                float vo0 = V_c[s * KK + ll];
                float vo1 = V_c[s * KK + ll + 16];
                float msk = (s < nA) ? 1.f : 0.f;
                float d0 = fmaf(g0, inv, -vo0) * msk;
                float d1 = fmaf(g1, inv, -vo1) * msk;
                dv0[u] = d0; dv1[u] = d1;
                if (tid < 16) {
                    dv_s[cb][u * KK + ll]      = d0;
                    dv_s[cb][u * KK + ll + 16] = d1;
                    V_c[s * KK + ll]      = vo0 + d0;
                    V_c[s * KK + ll + 16] = vo1 + d1;
                }
            }
        } else {
            // ---- wave 7: stage next block's Cblk tile ----
            if (wid == 7) {
                int nb2 = (bi + 1) % nblkp, sn0 = nb2 * BT;
                int l = tid & 63;
                #pragma unroll
                for (int q = 0; q < 4; ++q) {
                    int idx = q * 64 + l;
                    cblk_s[pv][idx] =
                        Cact[(size_t)(sn0 + (idx >> 4)) * AST + (sn0 + (idx & 15))];
                }
            }
            // ---- bulk: rank-16 update of all rows except current block ----
            if (bi > 0) {
                int lane = tid - 64;            // 0..447
                int k4 = (tid & 7) * 4;
                int arow = lane >> 3;           // 0..55
                float4 dvv[BT];
                #pragma unroll
                for (int t = 0; t < BT; ++t)
                    dvv[t] = *(float4*)&dv_s[pv][t * KK + k4];
                for (int m = 0; m < 8; ++m) {
                    int a = arow + 56 * m;
                    if (a < nAp && (a >> 4) != blk) {
                        float4 w = *(float4*)&W_c[a * WST + k4];
                        #pragma unroll
                        for (int t = 0; t < BT; ++t) {
                            float c = Cact[(size_t)(sp0 + t) * AST + a];
                            fma4(w, c, dvv[t]);
                        }
                        if ((a >> 4) == pblk) {   // cancel self-term
                            float cd = -Cact[(size_t)a * AST + a];
                            float4 dd = *(float4*)&dv_s[pv][(a - sp0) * KK + k4];
                            fma4(w, cd, dd);
                        }
                        *(float4*)&W_c[a * WST + k4] = w;
                    }
                }
            }
        }
        __syncthreads();
    }

    // ---- epilogue: z_out ----
    int k = tid & 31, r = tid >> 5;
    float v0k = Vg[(size_t)b * NF * KK + k];
    for (int n = 1 + r; n <= NN; n += 16) {
        int ii = is_input[b * NN + n - 1];
        float res;
        if (ii == 1) {
            res = z[b * NN + n - 1];
        } else {
            int a = slot_s[n];
            float dot = V_c[a * KK + k] * v0k;
            #pragma unroll
            for (int off = 16; off; off >>= 1) dot += __shfl_xor(dot, off, 32);
            float ca = fminf(fmaxf(-dot, -1.f + 1e-6f), 1.f - 1e-6f);
            res = acosf(ca) * (1.f / PI_F);
        }
        if (k == 0) out[b * NN + n - 1] = res;
    }
}

extern "C" void kernel_launch(void* const* d_in, const int* in_sizes, int n_in,
                              void* d_out, int out_size, void* d_ws, size_t ws_size,
                              hipStream_t stream) {
    const float* coeff    = (const float*)d_in[0];
    const float* upper    = (const float*)d_in[1];
    const float* basis    = (const float*)d_in[2];
    const float* z        = (const float*)d_in[3];
    const int*   is_input = (const int*)d_in[4];
    const float* vraw     = (const float*)d_in[5];
    const int*   perm     = (const int*)d_in[6];
    float* out = (float*)d_out;

    float* ws   = (float*)d_ws;
    float* Ct   = ws;                             // 730*730
    float* V    = Ct + (size_t)NF * NF;           // 8*730*32
    float* Cact = V + (size_t)BV * NF * KK;       // 8*448*448
    float* Wc   = Cact + (size_t)BV * AST * AST;  // 8*448*32
    int*   act  = (int*)(Wc + (size_t)BV * AST * KK);  // 8*448
    int*   nAa  = act + BV * AST;                 // 8
    // total ws ≈ 9.8 MB

    build_C_kernel<<<dim3((NF * NF + 255) / 256), dim3(256), 0, stream>>>(coeff, upper, basis, Ct);
    init_V_kernel<<<dim3(730), dim3(256), 0, stream>>>(z, vraw, V);
    build_act_kernel<<<dim3(BV), dim3(64), 0, stream>>>(is_input, perm, act, nAa);
    gather_Cact_kernel<<<dim3(AST, BV), dim3(256), 0, stream>>>(Ct, act, Cact);
    init_W_kernel<<<dim3(AST / 8, BV), dim3(256), 0, stream>>>(Ct, act, nAa, V, Wc);
    mix_kernel<<<dim3(BV), dim3(MTH), 0, stream>>>(Cact, Wc, act, nAa, is_input, z, V, out);
}

// Round 5
// 787.040 us; speedup vs baseline: 5.5600x; 1.4556x over previous
//
#include <hip/hip_runtime.h>

#define NN   729
#define NF   730   // N+1
#define BV   8
#define KK   32
#define NBAS 40
#define MAXIT 10
#define PI_F 3.14159265358979323846f

#define MTH  512    // mix threads (8 waves)
#define BT   16     // steps per block
#define AST  448    // padded max active rows (mean ~365); CactT stride
#define WST  36     // W row stride (floats), breaks bank alignment

__device__ __forceinline__ void fma4(float4& a, float c, const float4& d) {
    a.x = fmaf(c, d.x, a.x); a.y = fmaf(c, d.y, a.y);
    a.z = fmaf(c, d.z, a.z); a.w = fmaf(c, d.w, a.w);
}

// ---------------- build Ct (730x730), Ct[i][j] = C[j][i] ----------------
__global__ void build_C_kernel(const float* __restrict__ coeff,
                               const float* __restrict__ upper,
                               const float* __restrict__ basis,
                               float* __restrict__ Ct) {
    int idx = blockIdx.x * blockDim.x + threadIdx.x;
    if (idx >= NF * NF) return;
    int i = idx / NF, j = idx - i * NF;   // (i,j) of C; coalesced basis reads
    float val;
    if (i == 0) {
        val = (j == 0) ? 0.f : upper[j - 1];
    } else if (j == 0) {
        val = upper[i - 1];
    } else {
        float acc = 0.f;
        const float* bp = basis + (size_t)(i - 1) * NN + (j - 1);
        #pragma unroll 8
        for (int b = 0; b < NBAS; ++b)
            acc = fmaf(coeff[b], bp[(size_t)b * NN * NN], acc);
        val = acc;
    }
    Ct[(size_t)j * NF + i] = val;
}

// ---------------- init V  (B x 730 x 32) ----------------
__global__ void init_V_kernel(const float* __restrict__ z,
                              const float* __restrict__ vraw,
                              float* __restrict__ V) {
    int g = threadIdx.x >> 5;
    int k = threadIdx.x & 31;
    int row = blockIdx.x * 8 + g;           // 0..5839
    int b = row / NF, n = row - b * NF;
    const float* vr = vraw + (size_t)b * NF * KK;

    float v0 = vr[k];
    float s2 = v0 * v0;
    #pragma unroll
    for (int off = 16; off; off >>= 1) s2 += __shfl_xor(s2, off, 32);
    v0 = v0 / sqrtf(s2);

    float vn = vr[(size_t)n * KK + k];
    float d = vn * v0;
    #pragma unroll
    for (int off = 16; off; off >>= 1) d += __shfl_xor(d, off, 32);
    float u = vn - d * v0;
    float un2 = u * u;
    #pragma unroll
    for (int off = 16; off; off >>= 1) un2 += __shfl_xor(un2, off, 32);
    u = u / fmaxf(sqrtf(un2), 1e-8f);

    float zf = (n == 0) ? 1.f : z[b * NN + (n - 1)];
    float c = cosf(PI_F * zf), s = sinf(PI_F * zf);
    float outv = -c * v0 + s * u;
    if (n == 0) outv = v0;
    V[((size_t)b * NF + n) * KK + k] = outv;
}

// ---------------- build per-batch active lists (perm order) ----------------
__global__ void build_act_kernel(const int* __restrict__ is_input,
                                 const int* __restrict__ perm,
                                 int* __restrict__ act, int* __restrict__ nA_arr) {
    int b = blockIdx.x, l = threadIdx.x;   // 64 threads = 1 wave
    int base = 0;
    for (int c = 0; c < (NN + 63) / 64; ++c) {
        int idx = c * 64 + l;
        bool f = false; int pi = 0;
        if (idx < NN) { pi = perm[idx]; f = (is_input[b * NN + pi - 1] == 0); }
        unsigned long long m = __ballot(f);
        int pos = __popcll(m & ((1ull << l) - 1ull));
        if (f && base + pos < AST) act[b * AST + base + pos] = pi;
        base += __popcll(m);
    }
    if (base > AST) base = AST;
    if (l == 0) nA_arr[b] = base;
    for (int p = base + l; p < AST; p += 64) act[b * AST + p] = 0;
}

// --- gather CactT[b][a][t] = C[r_t][r_a] = Ct[r_a][r_t] (row-coalesced) ---
__global__ void gather_CactT_kernel(const float* __restrict__ Ct,
                                    const int* __restrict__ act,
                                    float* __restrict__ CactT) {
    int a = blockIdx.x, b = blockIdx.y;
    __shared__ int acts[AST];
    for (int i = threadIdx.x; i < AST; i += blockDim.x) acts[i] = act[b * AST + i];
    __syncthreads();
    const float* src = Ct + (size_t)acts[a] * NF;
    float* dst = CactT + ((size_t)b * AST + a) * AST;
    for (int t = threadIdx.x; t < AST; t += blockDim.x)
        dst[t] = src[acts[t]];
}

// ------- init W (compact): W[a] = sum_j Ct[ra][j] V[j] - Cd V[ra] -------
__global__ void init_W_kernel(const float* __restrict__ Ct,
                              const int* __restrict__ act,
                              const int* __restrict__ nA_arr,
                              const float* __restrict__ V,
                              float* __restrict__ Wc) {
    int b = blockIdx.y;
    int a = blockIdx.x * 8 + (threadIdx.x >> 5);
    int k = threadIdx.x & 31;
    int nA = nA_arr[b];
    float w = 0.f;
    if (a < nA) {
        int ra = act[b * AST + a];
        const float* ctr = Ct + (size_t)ra * NF;
        const float* vb = V + (size_t)b * NF * KK + k;
        float acc = 0.f;
        for (int j = 0; j < NF; ++j)
            acc = fmaf(ctr[j], vb[(size_t)j * KK], acc);
        float cd = ctr[ra];
        w = acc - cd * V[((size_t)b * NF + ra) * KK + k];
    }
    Wc[((size_t)b * AST + a) * KK + k] = w;
}

// 16-lane row sum via DPP row rotations (pure VALU)
__device__ __forceinline__ float rowsum16(float x) {
    int y;
    y = __builtin_amdgcn_update_dpp(0, __float_as_int(x), 0x121, 0xF, 0xF, false);
    x += __int_as_float(y);
    y = __builtin_amdgcn_update_dpp(0, __float_as_int(x), 0x122, 0xF, 0xF, false);
    x += __int_as_float(y);
    y = __builtin_amdgcn_update_dpp(0, __float_as_int(x), 0x124, 0xF, 0xF, false);
    x += __int_as_float(y);
    y = __builtin_amdgcn_update_dpp(0, __float_as_int(x), 0x128, 0xF, 0xF, false);
    x += __int_as_float(y);
    return x;
}

// ---------------- mixing ----------------
__global__ __launch_bounds__(MTH, 2)
void mix_kernel(const float* __restrict__ CactT_g,
                const float* __restrict__ Wc,
                const int* __restrict__ act_g,
                const int* __restrict__ nA_arr,
                const int* __restrict__ is_input,
                const float* __restrict__ z,
                const float* __restrict__ Vg,
                float* __restrict__ out) {
    __shared__ float W_c[AST * WST];      // 64512 B
    __shared__ float V_c[AST * KK];       // 57344 B
    __shared__ float dv_s[2][BT * KK];    // 4096 B
    __shared__ float cblk_s[2][BT * BT];  // 2048 B
    __shared__ int   act_s[AST];          // 1792 B
    __shared__ int   slot_s[NF];          // 2920 B

    int b = blockIdx.x, tid = threadIdx.x;
    const float* CactT_b = CactT_g + (size_t)b * AST * AST;
    int nA = nA_arr[b];
    int nblkp = (nA + BT - 1) / BT;
    if (nblkp < 2) nblkp = 2;            // data guarantees nA >> 16
    int nAp = nblkp * BT;
    int totB = MAXIT * nblkp;

    if (tid < AST) act_s[tid] = act_g[b * AST + tid];
    __syncthreads();
    for (int idx = tid; idx < nAp * KK; idx += MTH) {
        int a = idx >> 5, k = idx & 31;
        V_c[idx] = Vg[((size_t)b * NF + act_s[a]) * KK + k];
        W_c[a * WST + k] = Wc[((size_t)b * AST + a) * KK + k];
    }
    if (tid < nA) slot_s[act_s[tid]] = tid;
    if (tid < BT * BT)   // block-0 tile: cblk[t*16+u] = C[r_t][r_u] = CactT[u][t]
        cblk_s[0][tid] = CactT_b[(size_t)(tid & 15) * AST + (tid >> 4)];
    __syncthreads();

    int wid = tid >> 6;
    int laneb = tid - 64;                // bulk indices (junk for wave 0)
    int k4b = (laneb & 7) * 4;
    int ar = laneb >> 3;                 // 0..55

    float4 pfc[4];                       // wave0: next phase-A coefficients
    float4 cp[4][4];                     // bulk: pipelined c (4 m-chunks)
    if (wid > 0) {                       // prime pipeline for bi=1 (sp0 = 0)
        #pragma unroll
        for (int mm = 0; mm < 4; ++mm)
            #pragma unroll
            for (int j = 0; j < 4; ++j)
                cp[mm][j] = *(const float4*)&CactT_b[(size_t)(ar + 56 * mm) * AST + 4 * j];
    }

    for (int bi = 0; bi < totB; ++bi) {
        int blk = bi % nblkp;
        int s0 = blk * BT;
        int pblk = (bi - 1) % nblkp;     // valid when bi > 0
        int sp0 = pblk * BT;
        int cb = bi & 1, pv = cb ^ 1;

        if (wid == 0) {
            int u4 = tid >> 2, kq = (tid & 3) * 8;
            // ---- phase A: own block's 16 rows += prev dv (prefetched c) ----
            if (bi > 0) {
                float4 wA = *(float4*)&W_c[(s0 + u4) * WST + kq];
                float4 wB = *(float4*)&W_c[(s0 + u4) * WST + kq + 4];
                #pragma unroll
                for (int j = 0; j < 4; ++j) {
                    float4 cj = pfc[j];
                    float4 dA, dB;
                    dA = *(float4*)&dv_s[pv][(4*j+0) * KK + kq];
                    dB = *(float4*)&dv_s[pv][(4*j+0) * KK + kq + 4];
                    fma4(wA, cj.x, dA); fma4(wB, cj.x, dB);
                    dA = *(float4*)&dv_s[pv][(4*j+1) * KK + kq];
                    dB = *(float4*)&dv_s[pv][(4*j+1) * KK + kq + 4];
                    fma4(wA, cj.y, dA); fma4(wB, cj.y, dB);
                    dA = *(float4*)&dv_s[pv][(4*j+2) * KK + kq];
                    dB = *(float4*)&dv_s[pv][(4*j+2) * KK + kq + 4];
                    fma4(wA, cj.z, dA); fma4(wB, cj.z, dB);
                    dA = *(float4*)&dv_s[pv][(4*j+3) * KK + kq];
                    dB = *(float4*)&dv_s[pv][(4*j+3) * KK + kq + 4];
                    fma4(wA, cj.w, dA); fma4(wB, cj.w, dB);
                }
                *(float4*)&W_c[(s0 + u4) * WST + kq] = wA;
                *(float4*)&W_c[(s0 + u4) * WST + kq + 4] = wB;
            }
            // ---- prefetch phase-A c for next iteration ----
            {
                int s0n = ((bi + 1) % nblkp) * BT;
                #pragma unroll
                for (int j = 0; j < 4; ++j)
                    pfc[j] = *(const float4*)&CactT_b[(size_t)(s0n + u4) * AST + s0 + 4 * j];
            }
            __builtin_amdgcn_wave_barrier();

            // ---- serial: 16 steps, eager corrections, all in registers ----
            int ll = tid & 15;
            float g0[BT], g1[BT];
            #pragma unroll
            for (int u = 0; u < BT; ++u) {
                g0[u] = W_c[(s0 + u) * WST + ll];
                g1[u] = W_c[(s0 + u) * WST + ll + 16];
            }
            #pragma unroll
            for (int u = 0; u < BT; ++u) {
                int s = s0 + u;
                float n2 = fmaf(g0[u], g0[u], g1[u] * g1[u]);
                n2 = rowsum16(n2);
                float inv = -__builtin_amdgcn_rsqf(fmaxf(n2, 1e-16f));
                float vo0 = V_c[s * KK + ll];
                float vo1 = V_c[s * KK + ll + 16];
                float msk = (s < nA) ? 1.f : 0.f;
                float d0 = fmaf(g0[u], inv, -vo0) * msk;
                float d1 = fmaf(g1[u], inv, -vo1) * msk;
                if (tid < 16) {
                    dv_s[cb][u * KK + ll]      = d0;
                    dv_s[cb][u * KK + ll + 16] = d1;
                    V_c[s * KK + ll]      = vo0 + d0;
                    V_c[s * KK + ll + 16] = vo1 + d1;
                }
                #pragma unroll
                for (int u2 = u + 1; u2 < BT; ++u2) {
                    float c = cblk_s[cb][u * BT + u2];
                    g0[u2] = fmaf(c, d0, g0[u2]);
                    g1[u2] = fmaf(c, d1, g1[u2]);
                }
            }
        } else {
            // ---- wave 7 extra duty: stage next block's cblk tile ----
            if (wid == 7) {
                int sn0 = ((bi + 1) % nblkp) * BT;
                int l = tid & 63;
                #pragma unroll
                for (int qq = 0; qq < 4; ++qq) {
                    int idx = qq * 64 + l;   // idx = t*16+u
                    cblk_s[pv][idx] =
                        CactT_b[(size_t)(sn0 + (idx & 15)) * AST + sn0 + (idx >> 4)];
                }
            }
            // ---- bulk: rank-16 update, pipelined coalesced c loads ----
            if (bi > 0) {
                float4 dvv[BT];
                #pragma unroll
                for (int t = 0; t < BT; ++t)
                    dvv[t] = *(float4*)&dv_s[pv][t * KK + k4b];
                #pragma unroll
                for (int mm = 0; mm < 8; ++mm) {
                    int a = ar + 56 * mm;
                    int mb = mm & 3;
                    if (a < nAp && (a >> 4) != blk) {
                        float4 w = *(float4*)&W_c[a * WST + k4b];
                        #pragma unroll
                        for (int j = 0; j < 4; ++j) {
                            float4 cj = cp[mb][j];
                            fma4(w, cj.x, dvv[4*j+0]);
                            fma4(w, cj.y, dvv[4*j+1]);
                            fma4(w, cj.z, dvv[4*j+2]);
                            fma4(w, cj.w, dvv[4*j+3]);
                        }
                        if ((a >> 4) == pblk) {   // cancel self (diag) term
                            float cd = -CactT_b[(size_t)a * AST + a];
                            float4 dd = *(float4*)&dv_s[pv][(a - sp0) * KK + k4b];
                            fma4(w, cd, dd);
                        }
                        *(float4*)&W_c[a * WST + k4b] = w;
                    }
                    // prefetch: mm<4 -> (this bi, mm+4); mm>=4 -> (next bi, mm-4)
                    {
                        int col = (mm < 4) ? sp0 : s0;
                        int an  = (mm < 4) ? (a + 224) : (ar + 56 * (mm - 4));
                        #pragma unroll
                        for (int j = 0; j < 4; ++j)
                            cp[mb][j] = *(const float4*)&CactT_b[(size_t)an * AST + col + 4 * j];
                    }
                }
            }
        }
        __syncthreads();
    }

    // ---- epilogue: z_out ----
    int k = tid & 31, r = tid >> 5;
    float v0k = Vg[(size_t)b * NF * KK + k];
    for (int n = 1 + r; n <= NN; n += 16) {
        int ii = is_input[b * NN + n - 1];
        float res;
        if (ii == 1) {
            res = z[b * NN + n - 1];
        } else {
            int a = slot_s[n];
            float dot = V_c[a * KK + k] * v0k;
            #pragma unroll
            for (int off = 16; off; off >>= 1) dot += __shfl_xor(dot, off, 32);
            float ca = fminf(fmaxf(-dot, -1.f + 1e-6f), 1.f - 1e-6f);
            res = acosf(ca) * (1.f / PI_F);
        }
        if (k == 0) out[b * NN + n - 1] = res;
    }
}

extern "C" void kernel_launch(void* const* d_in, const int* in_sizes, int n_in,
                              void* d_out, int out_size, void* d_ws, size_t ws_size,
                              hipStream_t stream) {
    const float* coeff    = (const float*)d_in[0];
    const float* upper    = (const float*)d_in[1];
    const float* basis    = (const float*)d_in[2];
    const float* z        = (const float*)d_in[3];
    const int*   is_input = (const int*)d_in[4];
    const float* vraw     = (const float*)d_in[5];
    const int*   perm     = (const int*)d_in[6];
    float* out = (float*)d_out;

    float* ws    = (float*)d_ws;
    float* Ct    = ws;                              // 730*730
    float* V     = Ct + (size_t)NF * NF;            // 8*730*32
    float* CactT = V + (size_t)BV * NF * KK;        // 8*448*448
    float* Wc    = CactT + (size_t)BV * AST * AST;  // 8*448*32
    int*   act   = (int*)(Wc + (size_t)BV * AST * KK);  // 8*448
    int*   nAa   = act + BV * AST;                  // 8
    // total ws ≈ 9.8 MB

    build_C_kernel<<<dim3((NF * NF + 255) / 256), dim3(256), 0, stream>>>(coeff, upper, basis, Ct);
    init_V_kernel<<<dim3(730), dim3(256), 0, stream>>>(z, vraw, V);
    build_act_kernel<<<dim3(BV), dim3(64), 0, stream>>>(is_input, perm, act, nAa);
    gather_CactT_kernel<<<dim3(AST, BV), dim3(256), 0, stream>>>(Ct, act, CactT);
    init_W_kernel<<<dim3(AST / 8, BV), dim3(256), 0, stream>>>(Ct, act, nAa, V, Wc);
    mix_kernel<<<dim3(BV), dim3(MTH), 0, stream>>>(CactT, Wc, act, nAa, is_input, z, V, out);
}